// Round 8
// baseline (326.522 us; speedup 1.0000x reference)
//
#include <hip/hip_runtime.h>
#include <math.h>

// SPU transformer bounds propagation: elementwise, memory-bound target.
// In:  bounds[N][2] f32 (l,u).  Out: [N][6] f32.
//
// CORRECTNESS-CRITICAL: for l>=0 elements, areas a0 and a1 are EXACTLY equal
// in real arithmetic; jnp.argmin's tie-break is decided by f32 rounding of
// differently-ordered expressions. The l>=0 path is pure mul/add/div/sqrt --
// kept bit-identical to numpy via fp contract(off) + same association order.
// (Round-2 absmax=74 was FMA contraction flipping these ties.)
// ALSO: the m_lo/m_hi boundaries (x vs l+1e-5 / u-1e-5) gate a DISCONTINUOUS
// argmin flip; the division chain feeding x must stay IEEE f32.
//
// R7: TIMING PROBE -- kernel launched 3x per call (idempotent, graph-safe).
// kernel_time = (dur_R7 - dur_R5)/2 separates kernel from harness resets,
// which dominate dur_us (768 MiB poison fill alone is ~122 us).

__device__ __forceinline__ void spu_pair(float x, float& vs, float& tn) {
    #pragma clang fp contract(off)
    // branchless: sigmoid(-x) computed unconditionally (|x| small, no overflow)
    float e = expf(x);
    float s = 1.0f / (1.0f + e);          // sigmoid(-x)
    bool p = (x >= 0.0f);
    float t = x * x;
    vs = p ? (t - 0.5f) : (s - 1.0f);
    float tneg = (-s) * (1.0f - s);
    tn = p ? (2.0f * x) : tneg;
}

__device__ __forceinline__ void compute_one(float l, float u,
        float& r0, float& r1, float& r2, float& r3, float& r4, float& r5) {
    #pragma clang fp contract(off)
    float vs_l, tan_l, vs_u, tan_u;
    spu_pair(l, vs_l, tan_l);
    spu_pair(u, vs_u, tan_u);
    bool neg = (u < 0.0f);
    bool pos = (l >= 0.0f);
    bool cross = !(neg || pos);
    float all_slopes = (vs_u - vs_l) / (u - l);
    bool cross_neg = (all_slopes < 0.0f) && cross;
    bool cin_cross = (all_slopes < tan_l) && cross_neg;

    float slope_u = cin_cross ? tan_l : all_slopes;
    float su_l = slope_u * l;             // fl(slope_u*l)
    float shift_u = vs_l - su_l;          // pre-update value; used for x below
    if (cin_cross) {
        float t  = shift_u + 0.5f;
        float t4 = 4.0f * t;
        float s2 = slope_u * slope_u;
        float arg = s2 + t4;
        arg = fmaxf(arg, 0.0f);           // ref has no NaNs (finite threshold)
        float r = sqrtf(arg);
        float sr = slope_u + r;
        u = 0.5f * sr;                    // updated u used for areas/outputs
        spu_pair(u, vs_u, tan_u);
    }

    float pls_l = cross ? ((-0.5f - vs_l) / (-l)) : tan_l;
    float pls_u = tan_u;
    float pl_l = pls_l * l;
    float spls_l = vs_l - pl_l;
    float pu_u = pls_u * u;
    float spls_u = vs_u - pu_u;
    float cls = cross ? -0.5f : vs_l;
    float pl_u = pls_l * u;
    float y_u = pl_u + spls_l;
    float pu_l = pls_u * l;
    float y_l = pu_l + spls_u;
    float x = (cls - shift_u) / slope_u;
    bool m_hi = (x >= (u - 1e-5f));
    bool m_lo = (x <= (l + 1e-5f));
    float uml = u - l;
    float a0 = (0.5f * fabsf(y_u - vs_u)) * uml;    // ((0.5*|.|)*(u-l)) order
    float a1 = (0.5f * fabsf(y_l - vs_l)) * uml;
    float a2 = m_lo ? ((0.5f * fabsf(vs_u - cls)) * (u - x))
             : (m_hi ? ((0.5f * fabsf(vs_l - cls)) * (x - l)) : 0.0f);
    float cutoff = m_lo ? ((0.5f * fabsf(vs_l - cls)) * (l - x))
                 : (m_hi ? ((0.5f * fabsf(vs_u - cls)) * (x - u)) : 0.0f);
    if (m_hi) a2 = a2 - cutoff;
    if (m_lo) a2 = a2 - cutoff;           // both can apply, as in reference

    bool switched = (all_slopes < 0.0f);
    float out_l = switched ? vs_u : vs_l;
    float out_u = switched ? vs_l : vs_u;
    out_l = cross ? -0.5f : out_l;

    // jnp.argmin: first index of minimum
    int mai = (a0 <= a1 && a0 <= a2) ? 0 : ((a1 <= a2) ? 1 : 2);
    float slope_l = (mai == 0) ? pls_l : ((mai == 1) ? pls_u : 0.0f);
    float shift_l = (mai == 0) ? spls_l : ((mai == 1) ? spls_u : cls);

    r0 = out_l;
    r1 = out_u;
    r2 = neg ? slope_u : slope_l;
    r3 = neg ? slope_l : slope_u;
    r4 = neg ? shift_u : shift_l;
    r5 = neg ? shift_l : shift_u;
}

// 256 threads/block, 2 elements/thread -> 512 elements, 3072 out floats/block.
__global__ __launch_bounds__(256) void spu_transformer_kernel(
    const float* __restrict__ bounds, float* __restrict__ out, int n_elem) {
    __shared__ float sm[3072];            // 12 KiB staging for coalesced stores
    const int t = threadIdx.x;
    const int base = blockIdx.x * 512;    // first element of this block
    const int i0 = base + 2 * t;

    if (i0 + 1 < n_elem) {
        float4 b = reinterpret_cast<const float4*>(bounds)[(size_t)(base / 2) + t];
        float p0, p1, p2, p3, p4, p5;
        float q0, q1, q2, q3, q4, q5;
        compute_one(b.x, b.y, p0, p1, p2, p3, p4, p5);
        compute_one(b.z, b.w, q0, q1, q2, q3, q4, q5);
        float4* s4 = reinterpret_cast<float4*>(&sm[t * 12]);  // t*48B, 16B-aligned
        s4[0] = make_float4(p0, p1, p2, p3);
        s4[1] = make_float4(p4, p5, q0, q1);
        s4[2] = make_float4(q2, q3, q4, q5);
    } else if (i0 < n_elem) {             // odd tail element (not hit for N=2^23)
        float p0, p1, p2, p3, p4, p5;
        compute_one(bounds[2 * i0], bounds[2 * i0 + 1], p0, p1, p2, p3, p4, p5);
        sm[t * 12 + 0] = p0; sm[t * 12 + 1] = p1; sm[t * 12 + 2] = p2;
        sm[t * 12 + 3] = p3; sm[t * 12 + 4] = p4; sm[t * 12 + 5] = p5;
    }
    __syncthreads();

    const int nb = min(512, n_elem - base);    // elements in this block
    if (nb == 512) {
        // fully-coalesced: lane t writes float4 vectors t, t+256, t+512
        float4* o4 = reinterpret_cast<float4*>(out + (size_t)base * 6);
        const float4* s4 = reinterpret_cast<const float4*>(sm);
        o4[t]       = s4[t];
        o4[t + 256] = s4[t + 256];
        o4[t + 512] = s4[t + 512];
    } else {
        const int nf = nb * 6;
        for (int k = t; k < nf; k += 256) out[(size_t)base * 6 + k] = sm[k];
    }
}

extern "C" void kernel_launch(void* const* d_in, const int* in_sizes, int n_in,
                              void* d_out, int out_size, void* d_ws, size_t ws_size,
                              hipStream_t stream) {
    const float* bounds = (const float*)d_in[0];
    float* out = (float*)d_out;
    int n_elem = in_sizes[0] / 2;              // bounds is [N][2] flat
    int grid = (n_elem + 511) / 512;           // 512 elements per block
    // R7 probe: 3 identical launches (idempotent). kernel_time ~= (dur - dur_R5)/2.
    spu_transformer_kernel<<<grid, 256, 0, stream>>>(bounds, out, n_elem);
    spu_transformer_kernel<<<grid, 256, 0, stream>>>(bounds, out, n_elem);
    spu_transformer_kernel<<<grid, 256, 0, stream>>>(bounds, out, n_elem);
}